// Round 8
// baseline (636.381 us; speedup 1.0000x reference)
//
#include <hip/hip_runtime.h>
#include <stdint.h>

#define N_TOK    8192
#define DM       1024      // D_MODEL
#define DE       4096      // D_EXPERT
#define NEXP     8
#define CAP      2560
#define AUX_CO   0.01f
#define Z_CO     0.001f

typedef __attribute__((ext_vector_type(4))) float f32x4;
typedef __attribute__((ext_vector_type(8))) __bf16 bf16x8;

static __device__ __forceinline__ unsigned short f2bf(float f) {
  union { float f; uint32_t u; } v; v.f = f;
  uint32_t r = 0x7fffu + ((v.u >> 16) & 1u);
  return (unsigned short)((v.u + r) >> 16);
}
static __device__ __forceinline__ float bf2f(unsigned short u) {
  union { uint32_t u; float f; } v; v.u = ((uint32_t)u) << 16;
  return v.f;
}

#define MEMFENCE() asm volatile("" ::: "memory")
#define BAR()    do { MEMFENCE(); __builtin_amdgcn_s_barrier(); MEMFENCE(); } while (0)
#define LGKM0()  asm volatile("s_waitcnt lgkmcnt(0)" ::: "memory")
#define LGKM8()  asm volatile("s_waitcnt lgkmcnt(8)" ::: "memory")
#define VMW(N)   asm volatile("s_waitcnt vmcnt(" #N ")" ::: "memory")
#define SB0()    __builtin_amdgcn_sched_barrier(0)
#define GLD16(g, l) __builtin_amdgcn_global_load_lds( \
    (const __attribute__((address_space(1))) void*)(g), \
    (__attribute__((address_space(3))) void*)(l), 16, 0, 0)

// ------- transpose + fp32->bf16: in (R,C) -> out (C,R); 64x64 tiles, 16B ld/st -------
__global__ __launch_bounds__(256) void transpose_to_bf16(
    const float* __restrict__ in, unsigned short* __restrict__ out, int R, int C)
{
  __shared__ float tile[64][65];
  const size_t eoff = (size_t)blockIdx.z * R * C;
  const int bx = blockIdx.x * 64, by = blockIdx.y * 64;   // bx: C-dim, by: R-dim
  const int r = threadIdx.x >> 2, c16 = (threadIdx.x & 3) * 16;
#pragma unroll
  for (int j = 0; j < 4; ++j) {
    const float4 v = *(const float4*)&in[eoff + (size_t)(by + r) * C + bx + c16 + j * 4];
    tile[r][c16 + j * 4 + 0] = v.x; tile[r][c16 + j * 4 + 1] = v.y;
    tile[r][c16 + j * 4 + 2] = v.z; tile[r][c16 + j * 4 + 3] = v.w;
  }
  __syncthreads();
  const int oc = threadIdx.x >> 2, r16 = (threadIdx.x & 3) * 16;
#pragma unroll
  for (int half = 0; half < 2; ++half) {
    uint4 o;
    const int rb = r16 + half * 8;
    o.x = (uint32_t)f2bf(tile[rb + 0][oc]) | ((uint32_t)f2bf(tile[rb + 1][oc]) << 16);
    o.y = (uint32_t)f2bf(tile[rb + 2][oc]) | ((uint32_t)f2bf(tile[rb + 3][oc]) << 16);
    o.z = (uint32_t)f2bf(tile[rb + 4][oc]) | ((uint32_t)f2bf(tile[rb + 5][oc]) << 16);
    o.w = (uint32_t)f2bf(tile[rb + 6][oc]) | ((uint32_t)f2bf(tile[rb + 7][oc]) << 16);
    *(uint4*)&out[eoff + (size_t)(bx + oc) * R + by + rb] = o;
  }
}

// ---------------- router ----------------
__global__ __launch_bounds__(256) void router_kernel(
    const float* __restrict__ x, const float* __restrict__ Wr,
    int* __restrict__ topk, float* __restrict__ tkw, float* __restrict__ zP)
{
  const int tid = threadIdx.x, lane = tid & 63, wave = tid >> 6;
  float zacc = 0.f;
  float pacc[NEXP];
#pragma unroll
  for (int e = 0; e < NEXP; ++e) pacc[e] = 0.f;

  for (int it = 0; it < 4; ++it) {
    const int t = blockIdx.x * 16 + it * 4 + wave;
    float acc[NEXP];
#pragma unroll
    for (int e = 0; e < NEXP; ++e) acc[e] = 0.f;
    const f32x4* x4 = (const f32x4*)(x + (size_t)t * DM);
#pragma unroll
    for (int i = 0; i < 4; ++i) {
      f32x4 xv = x4[i * 64 + lane];
#pragma unroll
      for (int j = 0; j < 4; ++j) {
        const float xs = xv[j];
        const float* wr = Wr + (size_t)((i * 64 + lane) * 4 + j) * NEXP;
#pragma unroll
        for (int e = 0; e < NEXP; ++e) acc[e] += xs * wr[e];
      }
    }
#pragma unroll
    for (int m = 32; m; m >>= 1)
#pragma unroll
      for (int e = 0; e < NEXP; ++e) acc[e] += __shfl_xor(acc[e], m);

    float mx = acc[0];
#pragma unroll
    for (int e = 1; e < NEXP; ++e) mx = fmaxf(mx, acc[e]);
    float p[NEXP], s = 0.f;
#pragma unroll
    for (int e = 0; e < NEXP; ++e) { p[e] = expf(acc[e] - mx); s += p[e]; }
    const float lse = mx + logf(s);
    zacc += lse * lse;
    const float inv_s = 1.f / s;
#pragma unroll
    for (int e = 0; e < NEXP; ++e) pacc[e] += p[e] * inv_s;

    int e0 = 0; float v0 = p[0];
#pragma unroll
    for (int e = 1; e < NEXP; ++e) if (p[e] > v0) { v0 = p[e]; e0 = e; }
    int e1 = -1; float v1 = -1.f;
#pragma unroll
    for (int e = 0; e < NEXP; ++e) if (e != e0 && p[e] > v1) { v1 = p[e]; e1 = e; }

    const float pr0 = v0 * inv_s, pr1 = v1 * inv_s;
    const float denom = fmaxf(pr0 + pr1, 1e-9f);
    if (lane == 0) {
      topk[2*t]   = e0; topk[2*t+1] = e1;
      tkw[2*t]    = pr0 / denom; tkw[2*t+1] = pr1 / denom;
    }
  }
  __shared__ float blk[4][9];
  if (lane == 0) {
    blk[wave][0] = zacc;
#pragma unroll
    for (int e = 0; e < NEXP; ++e) blk[wave][1 + e] = pacc[e];
  }
  __syncthreads();
  if (tid < 9)
    zP[blockIdx.x * 9 + tid] = blk[0][tid] + blk[1][tid] + blk[2][tid] + blk[3][tid];
}

// -------- scan: FCFS capacity positions; topk/tkw staged in LDS; inv tail-fill fused --------
__global__ __launch_bounds__(512) void scan_kernel(
    const int2* __restrict__ topk, const float2* __restrict__ tkw,
    int* __restrict__ posk, float* __restrict__ wts,
    int* __restrict__ inv, int* __restrict__ kept)
{
  __shared__ int2   stopk[N_TOK];
  __shared__ float2 stkw[N_TOK];
  const int tid = threadIdx.x;
  for (int j = tid; j < N_TOK; j += 512) { stopk[j] = topk[j]; stkw[j] = tkw[j]; }
  __syncthreads();

  const int lane = tid & 63;
  const int e = tid >> 6;                   // 8 waves = 8 experts
  int base = 0;
  const uint64_t below = (lane == 63) ? 0xFFFFFFFFFFFFFFFFull >> 1
                                      : ((1ull << lane) - 1ull);
  for (int i = 0; i < N_TOK / 64; ++i) {
    const int t = i * 64 + lane;
    const int2 ti = stopk[t];
    const float2 w = stkw[t];
    const bool hit = (ti.x == e) || (ti.y == e);
    const uint64_t m = __ballot(hit);
    if (hit) {
      const int pos = base + (int)__popcll(m & below);
      const bool kp = pos < CAP;
      const int k = (ti.x == e) ? 0 : 1;
      posk[2*t + k] = kp ? pos : CAP;
      wts[2*t + k]  = kp ? ((k == 0) ? w.x : w.y) : 0.f;
      if (kp) inv[e * CAP + pos] = t;
    }
    base += (int)__popcll(m);
  }
  const int tail = base < CAP ? base : CAP;
  for (int q = tail + lane; q < CAP; q += 64) inv[e * CAP + q] = -1;
  if (lane == 0) kept[e] = tail;
}

// ---------------- dispatch ----------------
__global__ __launch_bounds__(256) void dispatch_kernel(
    const float* __restrict__ x, const int* __restrict__ inv,
    unsigned short* __restrict__ buf)
{
  const int slot = blockIdx.x;
  const int t = inv[slot];
  ushort4 o;
  if (t >= 0) {
    const f32x4 v = ((const f32x4*)(x + (size_t)t * DM))[threadIdx.x];
    o.x = f2bf(v[0]); o.y = f2bf(v[1]); o.z = f2bf(v[2]); o.w = f2bf(v[3]);
  } else {
    o.x = 0; o.y = 0; o.z = 0; o.w = 0;
  }
  ((ushort4*)(buf + (size_t)slot * DM))[threadIdx.x] = o;
}

// ========== 8-phase 256x256 grouped GEMM (proven: ~870 TF on GEMM1) ==========
template<bool RELU>
__global__ __launch_bounds__(512, 2) void gemm8p(
    const unsigned short* __restrict__ A,   // (E, M, K) bf16
    const unsigned short* __restrict__ Bt,  // (E, N, K) bf16
    const float* __restrict__ bias,         // (E, N)
    unsigned short* __restrict__ C,         // (E, M, N) bf16
    const int* __restrict__ kept,
    int M, int N, int K, int mt, int nt, int nwg)
{
  __shared__ __attribute__((aligned(16))) unsigned short As[2 * 16384];
  __shared__ __attribute__((aligned(16))) unsigned short Bs[2 * 16384];
  const int tid = threadIdx.x, lane = tid & 63, wave = tid >> 6;
  const int wr = wave >> 2, wc = wave & 3;
  const int frow = lane & 15, kgrp = lane >> 4;

  int wg = (int)blockIdx.x;
  wg = (wg & 7) * (nwg >> 3) + (wg >> 3);
  const int ntpe = mt * nt;
  const int e = wg / ntpe, rr = wg % ntpe;
  const int m0 = (rr / nt) * 256;
  const int n0 = (rr % nt) * 256;
  if (m0 >= kept[e]) return;

  const unsigned short* Ae = A  + (size_t)e * M * K + (size_t)m0 * K;
  const unsigned short* Be = Bt + (size_t)e * N * K + (size_t)n0 * K;

  const int srow = tid >> 3;
  const int scol = ((tid & 7) ^ (srow & 7)) * 8;

  auto stA = [&](int t, int h) {
    const int c = t & 1, k0 = t * 64;
#pragma unroll
    for (int i = 0; i < 2; ++i)
      GLD16(Ae + (size_t)(h * 128 + i * 64 + srow) * K + (k0 + scol),
            &As[c * 16384 + (h * 128 + i * 64) * 64 + tid * 8]);
  };
  auto stB = [&](int t, int h) {
    const int c = t & 1, k0 = t * 64;
#pragma unroll
    for (int i = 0; i < 2; ++i)
      GLD16(Be + (size_t)(h * 128 + i * 64 + srow) * K + (k0 + scol),
            &Bs[c * 16384 + (h * 128 + i * 64) * 64 + tid * 8]);
  };
  auto rdA = [&](bf16x8* dst, int c, int mh) {   // 8 ds_read_b128
#pragma unroll
    for (int m = 0; m < 4; ++m) {
      const int row = wr * 128 + mh * 64 + m * 16 + frow;
#pragma unroll
      for (int kk = 0; kk < 2; ++kk)
        dst[m * 2 + kk] = *(const bf16x8*)
          &As[c * 16384 + row * 64 + (((kk * 4 + kgrp) ^ (row & 7)) * 8)];
    }
  };
  auto rdB = [&](bf16x8* dst, int c, int nh) {   // 4 ds_read_b128
#pragma unroll
    for (int n = 0; n < 2; ++n) {
      const int row = wc * 64 + nh * 32 + n * 16 + frow;
#pragma unroll
      for (int kk = 0; kk < 2; ++kk)
        dst[n * 2 + kk] = *(const bf16x8*)
          &Bs[c * 16384 + row * 64 + (((kk * 4 + kgrp) ^ (row & 7)) * 8)];
    }
  };

  f32x4 acc[8][4];
#pragma unroll
  for (int m = 0; m < 8; ++m)
#pragma unroll
    for (int n = 0; n < 4; ++n) acc[m][n] = (f32x4){0.f, 0.f, 0.f, 0.f};

  bf16x8 af0[8], af1[8], bq0[4], bq1[4];
  auto mfmaQ = [&](int mh, int nh, bf16x8* af, bf16x8* bq) {  // 16 MFMA
#pragma unroll
    for (int m = 0; m < 4; ++m)
#pragma unroll
      for (int n = 0; n < 2; ++n)
#pragma unroll
        for (int kk = 0; kk < 2; ++kk)
          acc[mh * 4 + m][nh * 2 + n] = __builtin_amdgcn_mfma_f32_16x16x32_bf16(
              af[m * 2 + kk], bq[n * 2 + kk], acc[mh * 4 + m][nh * 2 + n], 0, 0, 0);
  };

  const int nk = K >> 6;

  stA(0, 0); stA(0, 1); stB(0, 0); stB(0, 1);
  stA(1, 0); stA(1, 1); stB(1, 0);
  VMW(6);
  BAR();

  for (int t = 0; t < nk; ++t) {
    const int c = t & 1;
    rdA(af0, c, 0);
    rdB(bq0, c, 0);
    if (t + 1 < nk) stB(t + 1, 1);
    LGKM8();
    BAR(); LGKM0(); SB0();
    __builtin_amdgcn_s_setprio(1);
    mfmaQ(0, 0, af0, bq0);
    __builtin_amdgcn_s_setprio(0);
    BAR();
    rdA(af1, c, 1);
    BAR(); LGKM0(); SB0();
    __builtin_amdgcn_s_setprio(1);
    mfmaQ(1, 0, af1, bq0);
    __builtin_amdgcn_s_setprio(0);
    BAR();
    rdB(bq1, c, 1);
    if (t + 2 < nk) stA(t + 2, 0);
    BAR(); LGKM0(); SB0();
    __builtin_amdgcn_s_setprio(1);
    mfmaQ(0, 1, af0, bq1);
    __builtin_amdgcn_s_setprio(0);
    BAR();
    if (t + 2 < nk) { stA(t + 2, 1); stB(t + 2, 0); }
    BAR(); SB0();
    __builtin_amdgcn_s_setprio(1);
    mfmaQ(1, 1, af1, bq1);
    __builtin_amdgcn_s_setprio(0);
    if (t + 2 < nk)      { VMW(6); }
    else if (t + 1 < nk) { VMW(0); }
    if (t + 1 < nk) BAR();
  }

  const int r0 = m0 + wr * 128 + 4 * kgrp;
  const int c0 = n0 + wc * 64 + frow;
#pragma unroll
  for (int nf = 0; nf < 4; ++nf) {
    const int cc = c0 + nf * 16;
    const float bv = bias[(size_t)e * N + cc];
#pragma unroll
    for (int m = 0; m < 8; ++m) {
#pragma unroll
      for (int r = 0; r < 4; ++r) {
        float v = acc[m][nf][r] + bv;
        if (RELU) v = fmaxf(v, 0.f);
        C[((size_t)e * M + (r0 + m * 16 + r)) * N + cc] = f2bf(v);
      }
    }
  }
}

// ========== 8-phase 320x128 grouped GEMM (GEMM2: 512 blocks = 2 balanced rounds) ==========
// Quadrants (0,0),(0,1),(1,0),(1,1) -> one A-half live. Stages: ph1 B(t+1)x2,
// ph2 A(t+2)g0, ph4 A(t+2)g1-g4. Per-tile 7 loads; steady VMW(5) drains A(t+1)+B(t+1).
// Hazards: g0 disjoint from ph3's A-h1 rows {80-159,240-319}; g1-g4 staged after ph3 BAR.
template<bool RELU>
__global__ __launch_bounds__(512, 2) void gemm8w(
    const unsigned short* __restrict__ A,   // (E, M, K) bf16
    const unsigned short* __restrict__ Bt,  // (E, N, K) bf16
    const float* __restrict__ bias,         // (E, N)
    unsigned short* __restrict__ C,         // (E, M, N) bf16
    const int* __restrict__ kept,
    int M, int N, int K, int mt, int nt, int nwg)
{
  __shared__ __attribute__((aligned(16))) unsigned short As[2 * 20480];  // 80 KB
  __shared__ __attribute__((aligned(16))) unsigned short Bs[2 * 8192];   // 32 KB
  const int tid = threadIdx.x, lane = tid & 63, wave = tid >> 6;
  const int wr = wave >> 2, wc = wave & 3;            // 2M x 4N
  const int frow = lane & 15, kgrp = lane >> 4;

  int wg = (int)blockIdx.x;
  wg = (wg & 7) * (nwg >> 3) + (wg >> 3);
  const int ntpe = mt * nt;
  const int e = wg / ntpe, rr = wg % ntpe;
  const int m0 = (rr / nt) * 320;
  const int n0 = (rr % nt) * 128;
  if (m0 >= kept[e]) return;

  const unsigned short* Ae = A  + (size_t)e * M * K + (size_t)m0 * K;
  const unsigned short* Be = Bt + (size_t)e * N * K + (size_t)n0 * K;

  const int srow = tid >> 3;
  const int scol = ((tid & 7) ^ (srow & 7)) * 8;

  auto stA = [&](int t, int g) {                       // one 64-row group
    const int c = t & 1, k0 = t * 64;
    GLD16(Ae + (size_t)(g * 64 + srow) * K + (k0 + scol),
          &As[c * 20480 + g * 4096 + tid * 8]);
  };
  auto stB = [&](int t) {                              // full 128-row B tile (2 gld)
    const int c = t & 1, k0 = t * 64;
#pragma unroll
    for (int i = 0; i < 2; ++i)
      GLD16(Be + (size_t)(i * 64 + srow) * K + (k0 + scol),
            &Bs[c * 8192 + i * 4096 + tid * 8]);
  };
  auto rdA = [&](bf16x8* dst, int c, int mh) {         // 5 frags x 2kk = 10 ds_read
#pragma unroll
    for (int m = 0; m < 5; ++m) {
      const int row = wr * 160 + mh * 80 + m * 16 + frow;
#pragma unroll
      for (int kk = 0; kk < 2; ++kk)
        dst[m * 2 + kk] = *(const bf16x8*)
          &As[c * 20480 + row * 64 + (((kk * 4 + kgrp) ^ (row & 7)) * 8)];
    }
  };
  auto rdB = [&](bf16x8* dst, int c, int nh) {         // 1 frag x 2kk = 2 ds_read
    const int row = wc * 32 + nh * 16 + frow;
#pragma unroll
    for (int kk = 0; kk < 2; ++kk)
      dst[kk] = *(const bf16x8*)
        &Bs[c * 8192 + row * 64 + (((kk * 4 + kgrp) ^ (row & 7)) * 8)];
  };

  f32x4 acc[10][2];
#pragma unroll
  for (int m = 0; m < 10; ++m)
#pragma unroll
    for (int n = 0; n < 2; ++n) acc[m][n] = (f32x4){0.f, 0.f, 0.f, 0.f};

  bf16x8 af[10], bq0[2], bq1[2];
  auto mfmaQ = [&](int mh, int nh, bf16x8* bq) {       // 10 MFMA
#pragma unroll
    for (int m = 0; m < 5; ++m)
#pragma unroll
      for (int kk = 0; kk < 2; ++kk)
        acc[mh * 5 + m][nh] = __builtin_amdgcn_mfma_f32_16x16x32_bf16(
            af[m * 2 + kk], bq[kk], acc[mh * 5 + m][nh], 0, 0, 0);
  };

  const int nk = K >> 6;   // 64 for GEMM2

  // prologue: A0 g0-g4, B0 x2, A1 g0-g4 -> 12 outstanding; drain A0+B0, keep A1 x5
  stA(0, 0); stA(0, 1); stA(0, 2); stA(0, 3); stA(0, 4);
  stB(0);
  stA(1, 0); stA(1, 1); stA(1, 2); stA(1, 3); stA(1, 4);
  VMW(5);
  BAR();

  for (int t = 0; t < nk; ++t) {
    const int c = t & 1;
    // ph1: rdA(h0)[10]+rdB(bq0)[2]; stage B(t+1); MFMA Q(0,0)
    rdA(af, c, 0);
    rdB(bq0, c, 0);
    if (t + 1 < nk) stB(t + 1);
    LGKM8();
    BAR(); LGKM0(); SB0();
    __builtin_amdgcn_s_setprio(1);
    mfmaQ(0, 0, bq0);
    __builtin_amdgcn_s_setprio(0);
    BAR();
    // ph2: rdB(bq1)[2]; stage A(t+2)g0 (disjoint from ph3 h1 rows); MFMA Q(0,1)
    rdB(bq1, c, 1);
    if (t + 2 < nk) stA(t + 2, 0);
    BAR(); LGKM0(); SB0();
    __builtin_amdgcn_s_setprio(1);
    mfmaQ(0, 1, bq1);
    __builtin_amdgcn_s_setprio(0);
    BAR();
    // ph3: rdA(h1)[10] (af reuse); MFMA Q(1,0)
    rdA(af, c, 1);
    BAR(); LGKM0(); SB0();
    __builtin_amdgcn_s_setprio(1);
    mfmaQ(1, 0, bq0);
    __builtin_amdgcn_s_setprio(0);
    BAR();
    // ph4: stage A(t+2) g1-g4 (all h reads drained); MFMA Q(1,1); counted vmcnt
    if (t + 2 < nk) { stA(t + 2, 1); stA(t + 2, 2); stA(t + 2, 3); stA(t + 2, 4); }
    BAR(); SB0();
    __builtin_amdgcn_s_setprio(1);
    mfmaQ(1, 1, bq1);
    __builtin_amdgcn_s_setprio(0);
    if (t + 2 < nk)      { VMW(5); }
    else if (t + 1 < nk) { VMW(0); }
    if (t + 1 < nk) BAR();
  }

  const int r0 = m0 + wr * 160 + 4 * kgrp;
  const int c0 = n0 + wc * 32 + frow;
#pragma unroll
  for (int nf = 0; nf < 2; ++nf) {
    const int cc = c0 + nf * 16;
    const float bv = bias[(size_t)e * N + cc];
#pragma unroll
    for (int m = 0; m < 10; ++m) {
#pragma unroll
      for (int r = 0; r < 4; ++r) {
        float v = acc[m][nf][r] + bv;
        if (RELU) v = fmaxf(v, 0.f);
        C[((size_t)e * M + (r0 + m * 16 + r)) * N + cc] = f2bf(v);
      }
    }
  }
}

// ---------------- combine (+ fused scalar finalize in block 0) ----------------
__global__ __launch_bounds__(256) void combine_kernel(
    const unsigned short* __restrict__ eo, const int* __restrict__ posk,
    const float* __restrict__ wts, const int* __restrict__ topk,
    const float* __restrict__ zP, const int* __restrict__ kept,
    float* __restrict__ out, float* __restrict__ outs)
{
  const int t = blockIdx.x;
  const int e0 = topk[2*t], e1 = topk[2*t+1];
  int p0 = posk[2*t], p1 = posk[2*t+1];
  p0 = p0 < CAP - 1 ? p0 : CAP - 1;
  p1 = p1 < CAP - 1 ? p1 : CAP - 1;
  const float w0 = wts[2*t], w1 = wts[2*t+1];
  const ushort4 a = ((const ushort4*)(eo + ((size_t)e0 * CAP + p0) * DM))[threadIdx.x];
  const ushort4 b = ((const ushort4*)(eo + ((size_t)e1 * CAP + p1) * DM))[threadIdx.x];
  f32x4 o;
  o[0] = w0 * bf2f(a.x) + w1 * bf2f(b.x);
  o[1] = w0 * bf2f(a.y) + w1 * bf2f(b.y);
  o[2] = w0 * bf2f(a.z) + w1 * bf2f(b.z);
  o[3] = w0 * bf2f(a.w) + w1 * bf2f(b.w);
  ((f32x4*)(out + (size_t)t * DM))[threadIdx.x] = o;

  if (t == 0 && threadIdx.x < 64) {
    const int lane = threadIdx.x;
    float v[9];
#pragma unroll
    for (int e = 0; e < 9; ++e) {
      float s = 0.f;
      for (int bk = 0; bk < 8; ++bk) s += zP[(lane * 8 + bk) * 9 + e];
      v[e] = s;
    }
#pragma unroll
    for (int m = 32; m; m >>= 1)
#pragma unroll
      for (int e = 0; e < 9; ++e) v[e] += __shfl_xor(v[e], m);
    if (lane == 0) {
      const float z = v[0] / (float)N_TOK;
      float total = 0.f;
      for (int e = 0; e < NEXP; ++e) total += (float)kept[e];
      total = fmaxf(total, 1.f);
      float aux = 0.f;
      for (int e = 0; e < NEXP; ++e)
        aux += ((float)kept[e] / total) * (v[1 + e] / (float)N_TOK);
      aux *= (float)NEXP;
      outs[0] = aux;
      outs[1] = z;
      outs[2] = AUX_CO * aux + Z_CO * z;
    }
  }
}

extern "C" void kernel_launch(void* const* d_in, const int* in_sizes, int n_in,
                              void* d_out, int out_size, void* d_ws, size_t ws_size,
                              hipStream_t stream)
{
  const float* x  = (const float*)d_in[0];
  const float* Wr = (const float*)d_in[1];
  const float* W1 = (const float*)d_in[2];
  const float* b1 = (const float*)d_in[3];
  const float* W2 = (const float*)d_in[4];
  const float* b2 = (const float*)d_in[5];
  float* out = (float*)d_out;

  char* p = (char*)d_ws;
  auto alloc = [&](size_t bytes) {
    char* q = p; p += (bytes + 255) & ~(size_t)255; return q;
  };
  unsigned short* W1t = (unsigned short*)alloc((size_t)NEXP * DM * DE * 2);   // (E, DE, DM)
  unsigned short* W2t = (unsigned short*)alloc((size_t)NEXP * DM * DE * 2);   // (E, DM, DE)
  unsigned short* buf = (unsigned short*)alloc((size_t)NEXP * CAP * DM * 2);  // (E, cap, DM)
  unsigned short* h   = (unsigned short*)alloc((size_t)NEXP * CAP * DE * 2);  // (E, cap, DE)
  unsigned short* eo  = (unsigned short*)alloc((size_t)NEXP * CAP * DM * 2);  // (E, cap, DM)
  int*   topk = (int*)alloc((size_t)N_TOK * 2 * 4);
  float* tkw  = (float*)alloc((size_t)N_TOK * 2 * 4);
  int*   posk = (int*)alloc((size_t)N_TOK * 2 * 4);
  float* wts  = (float*)alloc((size_t)N_TOK * 2 * 4);
  int*   inv  = (int*)alloc((size_t)NEXP * CAP * 4);
  int*   kept = (int*)alloc((size_t)NEXP * 4);
  float* zP   = (float*)alloc((size_t)512 * 9 * 4);

  transpose_to_bf16<<<dim3(DE / 64, DM / 64, NEXP), 256, 0, stream>>>(W1, W1t, DM, DE);
  transpose_to_bf16<<<dim3(DM / 64, DE / 64, NEXP), 256, 0, stream>>>(W2, W2t, DE, DM);
  router_kernel<<<512, 256, 0, stream>>>(x, Wr, topk, tkw, zP);
  scan_kernel<<<1, 512, 0, stream>>>((const int2*)topk, (const float2*)tkw, posk, wts, inv, kept);
  dispatch_kernel<<<NEXP * CAP, 256, 0, stream>>>(x, inv, buf);

  // GEMM1: 256^2 8-phase. 10m x 16n x 8e = 1280 wgs (5 balanced rounds).
  gemm8p<true><<<1280, 512, 0, stream>>>(buf, W1t, b1, h, kept, CAP, DE, DM, 10, 16, 1280);
  // GEMM2: 320x128 8-phase. 8m x 8n x 8e = 512 wgs (2 balanced rounds).
  gemm8w<false><<<512, 512, 0, stream>>>(h, W2t, b2, eo, kept, CAP, DM, DE, 8, 8, 512);

  combine_kernel<<<N_TOK, 256, 0, stream>>>(eo, posk, wts, topk, zP, kept,
                                            out, out + (size_t)N_TOK * DM);
}

// Round 9
// 587.713 us; speedup vs baseline: 1.0828x; 1.0828x over previous
//
#include <hip/hip_runtime.h>
#include <stdint.h>

#define N_TOK    8192
#define DM       1024      // D_MODEL
#define DE       4096      // D_EXPERT
#define NEXP     8
#define CAP      2560
#define AUX_CO   0.01f
#define Z_CO     0.001f

typedef __attribute__((ext_vector_type(4))) float f32x4;
typedef __attribute__((ext_vector_type(8))) __bf16 bf16x8;

static __device__ __forceinline__ unsigned short f2bf(float f) {
  union { float f; uint32_t u; } v; v.f = f;
  uint32_t r = 0x7fffu + ((v.u >> 16) & 1u);
  return (unsigned short)((v.u + r) >> 16);
}
static __device__ __forceinline__ float bf2f(unsigned short u) {
  union { uint32_t u; float f; } v; v.u = ((uint32_t)u) << 16;
  return v.f;
}

#define MEMFENCE() asm volatile("" ::: "memory")
#define BAR()    do { MEMFENCE(); __builtin_amdgcn_s_barrier(); MEMFENCE(); } while (0)
#define LGKM0()  asm volatile("s_waitcnt lgkmcnt(0)" ::: "memory")
#define LGKM8()  asm volatile("s_waitcnt lgkmcnt(8)" ::: "memory")
#define VMW(N)   asm volatile("s_waitcnt vmcnt(" #N ")" ::: "memory")
#define SB0()    __builtin_amdgcn_sched_barrier(0)
#define GLD16(g, l) __builtin_amdgcn_global_load_lds( \
    (const __attribute__((address_space(1))) void*)(g), \
    (__attribute__((address_space(3))) void*)(l), 16, 0, 0)

// ------- transpose + fp32->bf16: in (R,C) -> out (C,R); 64x64 tiles, 16B ld/st -------
__global__ __launch_bounds__(256) void transpose_to_bf16(
    const float* __restrict__ in, unsigned short* __restrict__ out, int R, int C)
{
  __shared__ float tile[64][65];
  const size_t eoff = (size_t)blockIdx.z * R * C;
  const int bx = blockIdx.x * 64, by = blockIdx.y * 64;   // bx: C-dim, by: R-dim
  const int r = threadIdx.x >> 2, c16 = (threadIdx.x & 3) * 16;
#pragma unroll
  for (int j = 0; j < 4; ++j) {
    const float4 v = *(const float4*)&in[eoff + (size_t)(by + r) * C + bx + c16 + j * 4];
    tile[r][c16 + j * 4 + 0] = v.x; tile[r][c16 + j * 4 + 1] = v.y;
    tile[r][c16 + j * 4 + 2] = v.z; tile[r][c16 + j * 4 + 3] = v.w;
  }
  __syncthreads();
  const int oc = threadIdx.x >> 2, r16 = (threadIdx.x & 3) * 16;
#pragma unroll
  for (int half = 0; half < 2; ++half) {
    uint4 o;
    const int rb = r16 + half * 8;
    o.x = (uint32_t)f2bf(tile[rb + 0][oc]) | ((uint32_t)f2bf(tile[rb + 1][oc]) << 16);
    o.y = (uint32_t)f2bf(tile[rb + 2][oc]) | ((uint32_t)f2bf(tile[rb + 3][oc]) << 16);
    o.z = (uint32_t)f2bf(tile[rb + 4][oc]) | ((uint32_t)f2bf(tile[rb + 5][oc]) << 16);
    o.w = (uint32_t)f2bf(tile[rb + 6][oc]) | ((uint32_t)f2bf(tile[rb + 7][oc]) << 16);
    *(uint4*)&out[eoff + (size_t)(bx + oc) * R + by + rb] = o;
  }
}

// ---------------- router ----------------
__global__ __launch_bounds__(256) void router_kernel(
    const float* __restrict__ x, const float* __restrict__ Wr,
    int* __restrict__ topk, float* __restrict__ tkw, float* __restrict__ zP)
{
  const int tid = threadIdx.x, lane = tid & 63, wave = tid >> 6;
  float zacc = 0.f;
  float pacc[NEXP];
#pragma unroll
  for (int e = 0; e < NEXP; ++e) pacc[e] = 0.f;

  for (int it = 0; it < 4; ++it) {
    const int t = blockIdx.x * 16 + it * 4 + wave;
    float acc[NEXP];
#pragma unroll
    for (int e = 0; e < NEXP; ++e) acc[e] = 0.f;
    const f32x4* x4 = (const f32x4*)(x + (size_t)t * DM);
#pragma unroll
    for (int i = 0; i < 4; ++i) {
      f32x4 xv = x4[i * 64 + lane];
#pragma unroll
      for (int j = 0; j < 4; ++j) {
        const float xs = xv[j];
        const float* wr = Wr + (size_t)((i * 64 + lane) * 4 + j) * NEXP;
#pragma unroll
        for (int e = 0; e < NEXP; ++e) acc[e] += xs * wr[e];
      }
    }
#pragma unroll
    for (int m = 32; m; m >>= 1)
#pragma unroll
      for (int e = 0; e < NEXP; ++e) acc[e] += __shfl_xor(acc[e], m);

    float mx = acc[0];
#pragma unroll
    for (int e = 1; e < NEXP; ++e) mx = fmaxf(mx, acc[e]);
    float p[NEXP], s = 0.f;
#pragma unroll
    for (int e = 0; e < NEXP; ++e) { p[e] = expf(acc[e] - mx); s += p[e]; }
    const float lse = mx + logf(s);
    zacc += lse * lse;
    const float inv_s = 1.f / s;
#pragma unroll
    for (int e = 0; e < NEXP; ++e) pacc[e] += p[e] * inv_s;

    int e0 = 0; float v0 = p[0];
#pragma unroll
    for (int e = 1; e < NEXP; ++e) if (p[e] > v0) { v0 = p[e]; e0 = e; }
    int e1 = -1; float v1 = -1.f;
#pragma unroll
    for (int e = 0; e < NEXP; ++e) if (e != e0 && p[e] > v1) { v1 = p[e]; e1 = e; }

    const float pr0 = v0 * inv_s, pr1 = v1 * inv_s;
    const float denom = fmaxf(pr0 + pr1, 1e-9f);
    if (lane == 0) {
      topk[2*t]   = e0; topk[2*t+1] = e1;
      tkw[2*t]    = pr0 / denom; tkw[2*t+1] = pr1 / denom;
    }
  }
  __shared__ float blk[4][9];
  if (lane == 0) {
    blk[wave][0] = zacc;
#pragma unroll
    for (int e = 0; e < NEXP; ++e) blk[wave][1 + e] = pacc[e];
  }
  __syncthreads();
  if (tid < 9)
    zP[blockIdx.x * 9 + tid] = blk[0][tid] + blk[1][tid] + blk[2][tid] + blk[3][tid];
}

// -------- scan: FCFS capacity positions; topk/tkw staged in LDS; inv tail-fill fused --------
__global__ __launch_bounds__(512) void scan_kernel(
    const int2* __restrict__ topk, const float2* __restrict__ tkw,
    int* __restrict__ posk, float* __restrict__ wts,
    int* __restrict__ inv, int* __restrict__ kept)
{
  __shared__ int2   stopk[N_TOK];
  __shared__ float2 stkw[N_TOK];
  const int tid = threadIdx.x;
  for (int j = tid; j < N_TOK; j += 512) { stopk[j] = topk[j]; stkw[j] = tkw[j]; }
  __syncthreads();

  const int lane = tid & 63;
  const int e = tid >> 6;                   // 8 waves = 8 experts
  int base = 0;
  const uint64_t below = (lane == 63) ? 0xFFFFFFFFFFFFFFFFull >> 1
                                      : ((1ull << lane) - 1ull);
  for (int i = 0; i < N_TOK / 64; ++i) {
    const int t = i * 64 + lane;
    const int2 ti = stopk[t];
    const float2 w = stkw[t];
    const bool hit = (ti.x == e) || (ti.y == e);
    const uint64_t m = __ballot(hit);
    if (hit) {
      const int pos = base + (int)__popcll(m & below);
      const bool kp = pos < CAP;
      const int k = (ti.x == e) ? 0 : 1;
      posk[2*t + k] = kp ? pos : CAP;
      wts[2*t + k]  = kp ? ((k == 0) ? w.x : w.y) : 0.f;
      if (kp) inv[e * CAP + pos] = t;
    }
    base += (int)__popcll(m);
  }
  const int tail = base < CAP ? base : CAP;
  for (int q = tail + lane; q < CAP; q += 64) inv[e * CAP + q] = -1;
  if (lane == 0) kept[e] = tail;
}

// ---------------- dispatch ----------------
__global__ __launch_bounds__(256) void dispatch_kernel(
    const float* __restrict__ x, const int* __restrict__ inv,
    unsigned short* __restrict__ buf)
{
  const int slot = blockIdx.x;
  const int t = inv[slot];
  ushort4 o;
  if (t >= 0) {
    const f32x4 v = ((const f32x4*)(x + (size_t)t * DM))[threadIdx.x];
    o.x = f2bf(v[0]); o.y = f2bf(v[1]); o.z = f2bf(v[2]); o.w = f2bf(v[3]);
  } else {
    o.x = 0; o.y = 0; o.z = 0; o.w = 0;
  }
  ((ushort4*)(buf + (size_t)slot * DM))[threadIdx.x] = o;
}

// ========== 8-phase 256x256 grouped GEMM with optional split-K (proven ~870 TF) ==========
// C[(split,e)](M,N) = A[e](M, lda).cols[split*K..] x Bt[e](N, lda).cols[split*K..]^T (+bias)
template<bool RELU, bool BIAS>
__global__ __launch_bounds__(512, 2) void gemm8p(
    const unsigned short* __restrict__ A,
    const unsigned short* __restrict__ Bt,
    const float* __restrict__ bias,         // (E, N) or null
    unsigned short* __restrict__ C,         // (nsplit, E, M, N) bf16
    const int* __restrict__ kept,
    int M, int N, int K, int lda, int mt, int nt, int nsplit, int nwg)
{
  __shared__ __attribute__((aligned(16))) unsigned short As[2 * 16384];
  __shared__ __attribute__((aligned(16))) unsigned short Bs[2 * 16384];
  const int tid = threadIdx.x, lane = tid & 63, wave = tid >> 6;
  const int wr = wave >> 2, wc = wave & 3;
  const int frow = lane & 15, kgrp = lane >> 4;

  int wg = (int)blockIdx.x;                 // bijective XCD chunking (nwg%8==0)
  wg = (wg & 7) * (nwg >> 3) + (wg >> 3);
  const int ntpe = mt * nt;
  const int bpe = ntpe * nsplit;
  const int e = wg / bpe;
  const int rem = wg % bpe;
  const int split = rem / ntpe;
  const int rr = rem % ntpe;
  const int m0 = (rr / nt) * 256;
  const int n0 = (rr % nt) * 256;
  if (m0 >= kept[e]) return;

  const unsigned short* Ae = A  + (size_t)e * M * lda + (size_t)m0 * lda + (size_t)split * K;
  const unsigned short* Be = Bt + (size_t)e * N * lda + (size_t)n0 * lda + (size_t)split * K;

  const int srow = tid >> 3;
  const int scol = ((tid & 7) ^ (srow & 7)) * 8;

  auto stA = [&](int t, int h) {
    const int c = t & 1, k0 = t * 64;
#pragma unroll
    for (int i = 0; i < 2; ++i)
      GLD16(Ae + (size_t)(h * 128 + i * 64 + srow) * lda + (k0 + scol),
            &As[c * 16384 + (h * 128 + i * 64) * 64 + tid * 8]);
  };
  auto stB = [&](int t, int h) {
    const int c = t & 1, k0 = t * 64;
#pragma unroll
    for (int i = 0; i < 2; ++i)
      GLD16(Be + (size_t)(h * 128 + i * 64 + srow) * lda + (k0 + scol),
            &Bs[c * 16384 + (h * 128 + i * 64) * 64 + tid * 8]);
  };
  auto rdA = [&](bf16x8* dst, int c, int mh) {   // 8 ds_read_b128
#pragma unroll
    for (int m = 0; m < 4; ++m) {
      const int row = wr * 128 + mh * 64 + m * 16 + frow;
#pragma unroll
      for (int kk = 0; kk < 2; ++kk)
        dst[m * 2 + kk] = *(const bf16x8*)
          &As[c * 16384 + row * 64 + (((kk * 4 + kgrp) ^ (row & 7)) * 8)];
    }
  };
  auto rdB = [&](bf16x8* dst, int c, int nh) {   // 4 ds_read_b128
#pragma unroll
    for (int n = 0; n < 2; ++n) {
      const int row = wc * 64 + nh * 32 + n * 16 + frow;
#pragma unroll
      for (int kk = 0; kk < 2; ++kk)
        dst[n * 2 + kk] = *(const bf16x8*)
          &Bs[c * 16384 + row * 64 + (((kk * 4 + kgrp) ^ (row & 7)) * 8)];
    }
  };

  f32x4 acc[8][4];
#pragma unroll
  for (int m = 0; m < 8; ++m)
#pragma unroll
    for (int n = 0; n < 4; ++n) acc[m][n] = (f32x4){0.f, 0.f, 0.f, 0.f};

  bf16x8 af0[8], af1[8], bq0[4], bq1[4];
  auto mfmaQ = [&](int mh, int nh, bf16x8* af, bf16x8* bq) {  // 16 MFMA
#pragma unroll
    for (int m = 0; m < 4; ++m)
#pragma unroll
      for (int n = 0; n < 2; ++n)
#pragma unroll
        for (int kk = 0; kk < 2; ++kk)
          acc[mh * 4 + m][nh * 2 + n] = __builtin_amdgcn_mfma_f32_16x16x32_bf16(
              af[m * 2 + kk], bq[n * 2 + kk], acc[mh * 4 + m][nh * 2 + n], 0, 0, 0);
  };

  const int nk = K >> 6;

  stA(0, 0); stA(0, 1); stB(0, 0); stB(0, 1);
  stA(1, 0); stA(1, 1); stB(1, 0);
  VMW(6);
  BAR();

  for (int t = 0; t < nk; ++t) {
    const int c = t & 1;
    rdA(af0, c, 0);
    rdB(bq0, c, 0);
    if (t + 1 < nk) stB(t + 1, 1);
    LGKM8();
    BAR(); LGKM0(); SB0();
    __builtin_amdgcn_s_setprio(1);
    mfmaQ(0, 0, af0, bq0);
    __builtin_amdgcn_s_setprio(0);
    BAR();
    rdA(af1, c, 1);
    BAR(); LGKM0(); SB0();
    __builtin_amdgcn_s_setprio(1);
    mfmaQ(1, 0, af1, bq0);
    __builtin_amdgcn_s_setprio(0);
    BAR();
    rdB(bq1, c, 1);
    if (t + 2 < nk) stA(t + 2, 0);
    BAR(); LGKM0(); SB0();
    __builtin_amdgcn_s_setprio(1);
    mfmaQ(0, 1, af0, bq1);
    __builtin_amdgcn_s_setprio(0);
    BAR();
    if (t + 2 < nk) { stA(t + 2, 1); stB(t + 2, 0); }
    BAR(); SB0();
    __builtin_amdgcn_s_setprio(1);
    mfmaQ(1, 1, af1, bq1);
    __builtin_amdgcn_s_setprio(0);
    if (t + 2 < nk)      { VMW(6); }
    else if (t + 1 < nk) { VMW(0); }
    if (t + 1 < nk) BAR();
  }

  unsigned short* Ce = C + (size_t)(split * NEXP + e) * M * N;
  const int r0 = m0 + wr * 128 + 4 * kgrp;
  const int c0 = n0 + wc * 64 + frow;
#pragma unroll
  for (int nf = 0; nf < 4; ++nf) {
    const int cc = c0 + nf * 16;
    float bv = 0.f;
    if (BIAS) bv = bias[(size_t)e * N + cc];
#pragma unroll
    for (int m = 0; m < 8; ++m) {
#pragma unroll
      for (int r = 0; r < 4; ++r) {
        float v = acc[m][nf][r] + bv;
        if (RELU) v = fmaxf(v, 0.f);
        Ce[(size_t)(r0 + m * 16 + r) * N + cc] = f2bf(v);
      }
    }
  }
}

// ------- combine: sum split-K partials + b2, weight by top-2; finalize fused in blk 0 -------
__global__ __launch_bounds__(256) void combine_kernel(
    const unsigned short* __restrict__ eo2,   // (2, E, CAP, DM) bf16 partials
    const float* __restrict__ b2,             // (E, DM)
    const int* __restrict__ posk, const float* __restrict__ wts,
    const int* __restrict__ topk,
    const float* __restrict__ zP, const int* __restrict__ kept,
    float* __restrict__ out, float* __restrict__ outs)
{
  const int t = blockIdx.x;
  const int e0 = topk[2*t], e1 = topk[2*t+1];
  int p0 = posk[2*t], p1 = posk[2*t+1];
  p0 = p0 < CAP - 1 ? p0 : CAP - 1;
  p1 = p1 < CAP - 1 ? p1 : CAP - 1;
  const float w0 = wts[2*t], w1 = wts[2*t+1];
  const size_t o0 = ((size_t)e0 * CAP + p0) * DM;
  const size_t o1 = ((size_t)e1 * CAP + p1) * DM;
  const size_t sp = (size_t)NEXP * CAP * DM;
  const ushort4 a0 = ((const ushort4*)(eo2 + o0))[threadIdx.x];
  const ushort4 a1 = ((const ushort4*)(eo2 + sp + o0))[threadIdx.x];
  const ushort4 c0 = ((const ushort4*)(eo2 + o1))[threadIdx.x];
  const ushort4 c1 = ((const ushort4*)(eo2 + sp + o1))[threadIdx.x];
  const f32x4 bv0 = ((const f32x4*)(b2 + (size_t)e0 * DM))[threadIdx.x];
  const f32x4 bv1 = ((const f32x4*)(b2 + (size_t)e1 * DM))[threadIdx.x];
  f32x4 o;
  o[0] = w0 * (bf2f(a0.x) + bf2f(a1.x) + bv0[0]) + w1 * (bf2f(c0.x) + bf2f(c1.x) + bv1[0]);
  o[1] = w0 * (bf2f(a0.y) + bf2f(a1.y) + bv0[1]) + w1 * (bf2f(c0.y) + bf2f(c1.y) + bv1[1]);
  o[2] = w0 * (bf2f(a0.z) + bf2f(a1.z) + bv0[2]) + w1 * (bf2f(c0.z) + bf2f(c1.z) + bv1[2]);
  o[3] = w0 * (bf2f(a0.w) + bf2f(a1.w) + bv0[3]) + w1 * (bf2f(c0.w) + bf2f(c1.w) + bv1[3]);
  ((f32x4*)(out + (size_t)t * DM))[threadIdx.x] = o;

  if (t == 0 && threadIdx.x < 64) {
    const int lane = threadIdx.x;
    float v[9];
#pragma unroll
    for (int e = 0; e < 9; ++e) {
      float s = 0.f;
      for (int bk = 0; bk < 8; ++bk) s += zP[(lane * 8 + bk) * 9 + e];
      v[e] = s;
    }
#pragma unroll
    for (int m = 32; m; m >>= 1)
#pragma unroll
      for (int e = 0; e < 9; ++e) v[e] += __shfl_xor(v[e], m);
    if (lane == 0) {
      const float z = v[0] / (float)N_TOK;
      float total = 0.f;
      for (int e = 0; e < NEXP; ++e) total += (float)kept[e];
      total = fmaxf(total, 1.f);
      float aux = 0.f;
      for (int e = 0; e < NEXP; ++e)
        aux += ((float)kept[e] / total) * (v[1 + e] / (float)N_TOK);
      aux *= (float)NEXP;
      outs[0] = aux;
      outs[1] = z;
      outs[2] = AUX_CO * aux + Z_CO * z;
    }
  }
}

extern "C" void kernel_launch(void* const* d_in, const int* in_sizes, int n_in,
                              void* d_out, int out_size, void* d_ws, size_t ws_size,
                              hipStream_t stream)
{
  const float* x  = (const float*)d_in[0];
  const float* Wr = (const float*)d_in[1];
  const float* W1 = (const float*)d_in[2];
  const float* b1 = (const float*)d_in[3];
  const float* W2 = (const float*)d_in[4];
  const float* b2 = (const float*)d_in[5];
  float* out = (float*)d_out;

  char* p = (char*)d_ws;
  auto alloc = [&](size_t bytes) {
    char* q = p; p += (bytes + 255) & ~(size_t)255; return q;
  };
  unsigned short* W1t = (unsigned short*)alloc((size_t)NEXP * DM * DE * 2);       // (E, DE, DM)
  unsigned short* W2t = (unsigned short*)alloc((size_t)NEXP * DM * DE * 2);       // (E, DM, DE)
  unsigned short* buf = (unsigned short*)alloc((size_t)NEXP * CAP * DM * 2);      // (E, cap, DM)
  unsigned short* h   = (unsigned short*)alloc((size_t)NEXP * CAP * DE * 2);      // (E, cap, DE)
  unsigned short* eo2 = (unsigned short*)alloc((size_t)2 * NEXP * CAP * DM * 2);  // (2, E, cap, DM)
  int*   topk = (int*)alloc((size_t)N_TOK * 2 * 4);
  float* tkw  = (float*)alloc((size_t)N_TOK * 2 * 4);
  int*   posk = (int*)alloc((size_t)N_TOK * 2 * 4);
  float* wts  = (float*)alloc((size_t)N_TOK * 2 * 4);
  int*   inv  = (int*)alloc((size_t)NEXP * CAP * 4);
  int*   kept = (int*)alloc((size_t)NEXP * 4);
  float* zP   = (float*)alloc((size_t)512 * 9 * 4);

  transpose_to_bf16<<<dim3(DE / 64, DM / 64, NEXP), 256, 0, stream>>>(W1, W1t, DM, DE);
  transpose_to_bf16<<<dim3(DM / 64, DE / 64, NEXP), 256, 0, stream>>>(W2, W2t, DE, DM);
  router_kernel<<<512, 256, 0, stream>>>(x, Wr, topk, tkw, zP);
  scan_kernel<<<1, 512, 0, stream>>>((const int2*)topk, (const float2*)tkw, posk, wts, inv, kept);
  dispatch_kernel<<<NEXP * CAP, 256, 0, stream>>>(x, inv, buf);

  // GEMM1: 256^2 8-phase, K=DM=1024 full. 10m x 16n x 8e = 1280 wgs.
  gemm8p<true, true><<<1280, 512, 0, stream>>>(
      buf, W1t, b1, h, kept, CAP, DE, DM, DM, 10, 16, 1, 1280);
  // GEMM2: 256^2 8-phase, split-K=2 (K=2048 each, lda=DE). 10m x 4n x 2k x 8e = 640 wgs.
  // Bias b2 is added in combine (once), partials are bf16.
  gemm8p<false, false><<<640, 512, 0, stream>>>(
      h, W2t, nullptr, eo2, kept, CAP, DM, DE / 2, DE, 10, 4, 2, 640);

  combine_kernel<<<N_TOK, 256, 0, stream>>>(eo2, b2, posk, wts, topk, zP, kept,
                                            out, out + (size_t)N_TOK * DM);
}

// Round 11
// 556.278 us; speedup vs baseline: 1.1440x; 1.0565x over previous
//
#include <hip/hip_runtime.h>
#include <stdint.h>

#define N_TOK    8192
#define DM       1024      // D_MODEL
#define DE       4096      // D_EXPERT
#define NEXP     8
#define CAP      2560
#define AUX_CO   0.01f
#define Z_CO     0.001f

typedef __attribute__((ext_vector_type(4))) float f32x4;
typedef __attribute__((ext_vector_type(8))) __bf16 bf16x8;

static __device__ __forceinline__ unsigned short f2bf(float f) {
  union { float f; uint32_t u; } v; v.f = f;
  uint32_t r = 0x7fffu + ((v.u >> 16) & 1u);
  return (unsigned short)((v.u + r) >> 16);
}
static __device__ __forceinline__ float bf2f(unsigned short u) {
  union { uint32_t u; float f; } v; v.u = ((uint32_t)u) << 16;
  return v.f;
}

#define MEMFENCE() asm volatile("" ::: "memory")
#define BAR()    do { MEMFENCE(); __builtin_amdgcn_s_barrier(); MEMFENCE(); } while (0)
#define LGKM0()  asm volatile("s_waitcnt lgkmcnt(0)" ::: "memory")
#define VMW(N)   asm volatile("s_waitcnt vmcnt(" #N ")" ::: "memory")
#define GLD16(g, l) __builtin_amdgcn_global_load_lds( \
    (const __attribute__((address_space(1))) void*)(g), \
    (__attribute__((address_space(3))) void*)(l), 16, 0, 0)

// ------- transpose + fp32->bf16: in (R,C) -> out (C,R); 64x64 tiles, 16B ld/st -------
__global__ __launch_bounds__(256) void transpose_to_bf16(
    const float* __restrict__ in, unsigned short* __restrict__ out, int R, int C)
{
  __shared__ float tile[64][65];
  const size_t eoff = (size_t)blockIdx.z * R * C;
  const int bx = blockIdx.x * 64, by = blockIdx.y * 64;   // bx: C-dim, by: R-dim
  const int r = threadIdx.x >> 2, c16 = (threadIdx.x & 3) * 16;
#pragma unroll
  for (int j = 0; j < 4; ++j) {
    const float4 v = *(const float4*)&in[eoff + (size_t)(by + r) * C + bx + c16 + j * 4];
    tile[r][c16 + j * 4 + 0] = v.x; tile[r][c16 + j * 4 + 1] = v.y;
    tile[r][c16 + j * 4 + 2] = v.z; tile[r][c16 + j * 4 + 3] = v.w;
  }
  __syncthreads();
  const int oc = threadIdx.x >> 2, r16 = (threadIdx.x & 3) * 16;
#pragma unroll
  for (int half = 0; half < 2; ++half) {
    uint4 o;
    const int rb = r16 + half * 8;
    o.x = (uint32_t)f2bf(tile[rb + 0][oc]) | ((uint32_t)f2bf(tile[rb + 1][oc]) << 16);
    o.y = (uint32_t)f2bf(tile[rb + 2][oc]) | ((uint32_t)f2bf(tile[rb + 3][oc]) << 16);
    o.z = (uint32_t)f2bf(tile[rb + 4][oc]) | ((uint32_t)f2bf(tile[rb + 5][oc]) << 16);
    o.w = (uint32_t)f2bf(tile[rb + 6][oc]) | ((uint32_t)f2bf(tile[rb + 7][oc]) << 16);
    *(uint4*)&out[eoff + (size_t)(bx + oc) * R + by + rb] = o;
  }
}

// ---------------- router ----------------
__global__ __launch_bounds__(256) void router_kernel(
    const float* __restrict__ x, const float* __restrict__ Wr,
    int* __restrict__ topk, float* __restrict__ tkw, float* __restrict__ zP)
{
  const int tid = threadIdx.x, lane = tid & 63, wave = tid >> 6;
  float zacc = 0.f;
  float pacc[NEXP];
#pragma unroll
  for (int e = 0; e < NEXP; ++e) pacc[e] = 0.f;

  for (int it = 0; it < 4; ++it) {
    const int t = blockIdx.x * 16 + it * 4 + wave;
    float acc[NEXP];
#pragma unroll
    for (int e = 0; e < NEXP; ++e) acc[e] = 0.f;
    const f32x4* x4 = (const f32x4*)(x + (size_t)t * DM);
#pragma unroll
    for (int i = 0; i < 4; ++i) {
      f32x4 xv = x4[i * 64 + lane];
#pragma unroll
      for (int j = 0; j < 4; ++j) {
        const float xs = xv[j];
        const float* wr = Wr + (size_t)((i * 64 + lane) * 4 + j) * NEXP;
#pragma unroll
        for (int e = 0; e < NEXP; ++e) acc[e] += xs * wr[e];
      }
    }
#pragma unroll
    for (int m = 32; m; m >>= 1)
#pragma unroll
      for (int e = 0; e < NEXP; ++e) acc[e] += __shfl_xor(acc[e], m);

    float mx = acc[0];
#pragma unroll
    for (int e = 1; e < NEXP; ++e) mx = fmaxf(mx, acc[e]);
    float p[NEXP], s = 0.f;
#pragma unroll
    for (int e = 0; e < NEXP; ++e) { p[e] = expf(acc[e] - mx); s += p[e]; }
    const float lse = mx + logf(s);
    zacc += lse * lse;
    const float inv_s = 1.f / s;
#pragma unroll
    for (int e = 0; e < NEXP; ++e) pacc[e] += p[e] * inv_s;

    int e0 = 0; float v0 = p[0];
#pragma unroll
    for (int e = 1; e < NEXP; ++e) if (p[e] > v0) { v0 = p[e]; e0 = e; }
    int e1 = -1; float v1 = -1.f;
#pragma unroll
    for (int e = 0; e < NEXP; ++e) if (e != e0 && p[e] > v1) { v1 = p[e]; e1 = e; }

    const float pr0 = v0 * inv_s, pr1 = v1 * inv_s;
    const float denom = fmaxf(pr0 + pr1, 1e-9f);
    if (lane == 0) {
      topk[2*t]   = e0; topk[2*t+1] = e1;
      tkw[2*t]    = pr0 / denom; tkw[2*t+1] = pr1 / denom;
    }
  }
  __shared__ float blk[4][9];
  if (lane == 0) {
    blk[wave][0] = zacc;
#pragma unroll
    for (int e = 0; e < NEXP; ++e) blk[wave][1 + e] = pacc[e];
  }
  __syncthreads();
  if (tid < 9)
    zP[blockIdx.x * 9 + tid] = blk[0][tid] + blk[1][tid] + blk[2][tid] + blk[3][tid];
}

// -------- scan: FCFS capacity positions; topk/tkw staged in LDS; inv tail-fill fused --------
__global__ __launch_bounds__(512) void scan_kernel(
    const int2* __restrict__ topk, const float2* __restrict__ tkw,
    int* __restrict__ posk, float* __restrict__ wts,
    int* __restrict__ inv, int* __restrict__ kept)
{
  __shared__ int2   stopk[N_TOK];
  __shared__ float2 stkw[N_TOK];
  const int tid = threadIdx.x;
  for (int j = tid; j < N_TOK; j += 512) { stopk[j] = topk[j]; stkw[j] = tkw[j]; }
  __syncthreads();

  const int lane = tid & 63;
  const int e = tid >> 6;                   // 8 waves = 8 experts
  int base = 0;
  const uint64_t below = (lane == 63) ? 0xFFFFFFFFFFFFFFFFull >> 1
                                      : ((1ull << lane) - 1ull);
  for (int i = 0; i < N_TOK / 64; ++i) {
    const int t = i * 64 + lane;
    const int2 ti = stopk[t];
    const float2 w = stkw[t];
    const bool hit = (ti.x == e) || (ti.y == e);
    const uint64_t m = __ballot(hit);
    if (hit) {
      const int pos = base + (int)__popcll(m & below);
      const bool kp = pos < CAP;
      const int k = (ti.x == e) ? 0 : 1;
      posk[2*t + k] = kp ? pos : CAP;
      wts[2*t + k]  = kp ? ((k == 0) ? w.x : w.y) : 0.f;
      if (kp) inv[e * CAP + pos] = t;
    }
    base += (int)__popcll(m);
  }
  const int tail = base < CAP ? base : CAP;
  for (int q = tail + lane; q < CAP; q += 64) inv[e * CAP + q] = -1;
  if (lane == 0) kept[e] = tail;
}

// ---------------- dispatch ----------------
__global__ __launch_bounds__(256) void dispatch_kernel(
    const float* __restrict__ x, const int* __restrict__ inv,
    unsigned short* __restrict__ buf)
{
  const int slot = blockIdx.x;
  const int t = inv[slot];
  ushort4 o;
  if (t >= 0) {
    const f32x4 v = ((const f32x4*)(x + (size_t)t * DM))[threadIdx.x];
    o.x = f2bf(v[0]); o.y = f2bf(v[1]); o.z = f2bf(v[2]); o.w = f2bf(v[3]);
  } else {
    o.x = 0; o.y = 0; o.z = 0; o.w = 0;
  }
  ((ushort4*)(buf + (size_t)slot * DM))[threadIdx.x] = o;
}

// ========== 2-barrier-per-tile 256x256 grouped GEMM (+ optional split-K) ==========
// Per K-tile: VMW(8) [2-tile-old loads ready] -> BAR -> 24 ds_read -> LGKM0 ->
// BAR [ALL waves' reads of buf c drained] -> stage(t+2) -> 64 MFMA uninterrupted.
// 2 barriers + 1 LGKM0 per tile (vs 8-phase's 8+3); counted vmcnt, never 0 mid-loop.
template<bool RELU, bool BIAS>
__global__ __launch_bounds__(512, 2) void gemm2b(
    const unsigned short* __restrict__ A,
    const unsigned short* __restrict__ Bt,
    const float* __restrict__ bias,         // (E, N) or null
    unsigned short* __restrict__ C,         // (nsplit, E, M, N) bf16
    const int* __restrict__ kept,
    int M, int N, int K, int lda, int mt, int nt, int nsplit, int nwg)
{
  __shared__ __attribute__((aligned(16))) unsigned short As[2 * 16384];
  __shared__ __attribute__((aligned(16))) unsigned short Bs[2 * 16384];
  const int tid = threadIdx.x, lane = tid & 63, wave = tid >> 6;
  const int wr = wave >> 2, wc = wave & 3;
  const int frow = lane & 15, kgrp = lane >> 4;

  int wg = (int)blockIdx.x;                 // bijective XCD chunking (nwg%8==0)
  wg = (wg & 7) * (nwg >> 3) + (wg >> 3);
  const int ntpe = mt * nt;
  const int bpe = ntpe * nsplit;
  const int e = wg / bpe;
  const int rem = wg % bpe;
  const int split = rem / ntpe;
  const int rr = rem % ntpe;
  const int m0 = (rr / nt) * 256;
  const int n0 = (rr % nt) * 256;
  if (m0 >= kept[e]) return;

  const unsigned short* Ae = A  + (size_t)e * M * lda + (size_t)m0 * lda + (size_t)split * K;
  const unsigned short* Be = Bt + (size_t)e * N * lda + (size_t)n0 * lda + (size_t)split * K;

  const int srow = tid >> 3;
  const int scol = ((tid & 7) ^ (srow & 7)) * 8;

  // full tile stage: 4 A + 4 B global_load_lds per thread
  auto stage = [&](int t) {
    const int c = t & 1, k0 = t * 64;
#pragma unroll
    for (int i = 0; i < 4; ++i)
      GLD16(Ae + (size_t)(i * 64 + srow) * lda + (k0 + scol),
            &As[c * 16384 + i * 4096 + tid * 8]);
#pragma unroll
    for (int i = 0; i < 4; ++i)
      GLD16(Be + (size_t)(i * 64 + srow) * lda + (k0 + scol),
            &Bs[c * 16384 + i * 4096 + tid * 8]);
  };
  auto rdA = [&](bf16x8* dst, int c, int mh) {   // 8 ds_read_b128
#pragma unroll
    for (int m = 0; m < 4; ++m) {
      const int row = wr * 128 + mh * 64 + m * 16 + frow;
#pragma unroll
      for (int kk = 0; kk < 2; ++kk)
        dst[m * 2 + kk] = *(const bf16x8*)
          &As[c * 16384 + row * 64 + (((kk * 4 + kgrp) ^ (row & 7)) * 8)];
    }
  };
  auto rdB = [&](bf16x8* dst, int c, int nh) {   // 4 ds_read_b128
#pragma unroll
    for (int n = 0; n < 2; ++n) {
      const int row = wc * 64 + nh * 32 + n * 16 + frow;
#pragma unroll
      for (int kk = 0; kk < 2; ++kk)
        dst[n * 2 + kk] = *(const bf16x8*)
          &Bs[c * 16384 + row * 64 + (((kk * 4 + kgrp) ^ (row & 7)) * 8)];
    }
  };

  f32x4 acc[8][4];
#pragma unroll
  for (int m = 0; m < 8; ++m)
#pragma unroll
    for (int n = 0; n < 4; ++n) acc[m][n] = (f32x4){0.f, 0.f, 0.f, 0.f};

  bf16x8 af0[8], af1[8], bq0[4], bq1[4];
  auto mfmaQ = [&](int mh, int nh, bf16x8* af, bf16x8* bq) {  // 16 MFMA
#pragma unroll
    for (int m = 0; m < 4; ++m)
#pragma unroll
      for (int n = 0; n < 2; ++n)
#pragma unroll
        for (int kk = 0; kk < 2; ++kk)
          acc[mh * 4 + m][nh * 2 + n] = __builtin_amdgcn_mfma_f32_16x16x32_bf16(
              af[m * 2 + kk], bq[n * 2 + kk], acc[mh * 4 + m][nh * 2 + n], 0, 0, 0);
  };

  const int nk = K >> 6;

  stage(0); stage(1);                        // 16 outstanding

  for (int t = 0; t < nk; ++t) {
    const int c = t & 1;
    // tile-t data (issued 2 tiles ago, drained to depth 8) ready
    if (t + 2 <= nk) { VMW(8); } else { VMW(0); }
    BAR();
    // all 24 fragment reads for this tile
    rdA(af0, c, 0);
    rdA(af1, c, 1);
    rdB(bq0, c, 0);
    rdB(bq1, c, 1);
    LGKM0();                                 // this wave's reads done
    BAR();                                   // ALL waves' reads of buf c done
    if (t + 2 < nk) stage(t + 2);            // now safe to overwrite buf c
    __builtin_amdgcn_s_setprio(1);
    mfmaQ(0, 0, af0, bq0);
    mfmaQ(0, 1, af0, bq1);
    mfmaQ(1, 0, af1, bq0);
    mfmaQ(1, 1, af1, bq1);
    __builtin_amdgcn_s_setprio(0);
  }

  unsigned short* Ce = C + (size_t)(split * NEXP + e) * M * N;
  const int r0 = m0 + wr * 128 + 4 * kgrp;
  const int c0 = n0 + wc * 64 + frow;
#pragma unroll
  for (int nf = 0; nf < 4; ++nf) {
    const int cc = c0 + nf * 16;
    float bv = 0.f;
    if (BIAS) bv = bias[(size_t)e * N + cc];
#pragma unroll
    for (int m = 0; m < 8; ++m) {
#pragma unroll
      for (int r = 0; r < 4; ++r) {
        float v = acc[m][nf][r] + bv;
        if (RELU) v = fmaxf(v, 0.f);
        Ce[(size_t)(r0 + m * 16 + r) * N + cc] = f2bf(v);
      }
    }
  }
}

// ------- combine: sum split-K partials + b2, weight by top-2; finalize fused in blk 0 -------
__global__ __launch_bounds__(256) void combine_kernel(
    const unsigned short* __restrict__ eo2,   // (2, E, CAP, DM) bf16 partials
    const float* __restrict__ b2,             // (E, DM)
    const int* __restrict__ posk, const float* __restrict__ wts,
    const int* __restrict__ topk,
    const float* __restrict__ zP, const int* __restrict__ kept,
    float* __restrict__ out, float* __restrict__ outs)
{
  const int t = blockIdx.x;
  const int e0 = topk[2*t], e1 = topk[2*t+1];
  int p0 = posk[2*t], p1 = posk[2*t+1];
  p0 = p0 < CAP - 1 ? p0 : CAP - 1;
  p1 = p1 < CAP - 1 ? p1 : CAP - 1;
  const float w0 = wts[2*t], w1 = wts[2*t+1];
  const size_t o0 = ((size_t)e0 * CAP + p0) * DM;
  const size_t o1 = ((size_t)e1 * CAP + p1) * DM;
  const size_t sp = (size_t)NEXP * CAP * DM;
  const ushort4 a0 = ((const ushort4*)(eo2 + o0))[threadIdx.x];
  const ushort4 a1 = ((const ushort4*)(eo2 + sp + o0))[threadIdx.x];
  const ushort4 c0 = ((const ushort4*)(eo2 + o1))[threadIdx.x];
  const ushort4 c1 = ((const ushort4*)(eo2 + sp + o1))[threadIdx.x];
  const f32x4 bv0 = ((const f32x4*)(b2 + (size_t)e0 * DM))[threadIdx.x];
  const f32x4 bv1 = ((const f32x4*)(b2 + (size_t)e1 * DM))[threadIdx.x];
  f32x4 o;
  o[0] = w0 * (bf2f(a0.x) + bf2f(a1.x) + bv0[0]) + w1 * (bf2f(c0.x) + bf2f(c1.x) + bv1[0]);
  o[1] = w0 * (bf2f(a0.y) + bf2f(a1.y) + bv0[1]) + w1 * (bf2f(c0.y) + bf2f(c1.y) + bv1[1]);
  o[2] = w0 * (bf2f(a0.z) + bf2f(a1.z) + bv0[2]) + w1 * (bf2f(c0.z) + bf2f(c1.z) + bv1[2]);
  o[3] = w0 * (bf2f(a0.w) + bf2f(a1.w) + bv0[3]) + w1 * (bf2f(c0.w) + bf2f(c1.w) + bv1[3]);
  ((f32x4*)(out + (size_t)t * DM))[threadIdx.x] = o;

  if (t == 0 && threadIdx.x < 64) {
    const int lane = threadIdx.x;
    float v[9];
#pragma unroll
    for (int e = 0; e < 9; ++e) {
      float s = 0.f;
      for (int bk = 0; bk < 8; ++bk) s += zP[(lane * 8 + bk) * 9 + e];
      v[e] = s;
    }
#pragma unroll
    for (int m = 32; m; m >>= 1)
#pragma unroll
      for (int e = 0; e < 9; ++e) v[e] += __shfl_xor(v[e], m);
    if (lane == 0) {
      const float z = v[0] / (float)N_TOK;
      float total = 0.f;
      for (int e = 0; e < NEXP; ++e) total += (float)kept[e];
      total = fmaxf(total, 1.f);
      float aux = 0.f;
      for (int e = 0; e < NEXP; ++e)
        aux += ((float)kept[e] / total) * (v[1 + e] / (float)N_TOK);
      aux *= (float)NEXP;
      outs[0] = aux;
      outs[1] = z;
      outs[2] = AUX_CO * aux + Z_CO * z;
    }
  }
}

extern "C" void kernel_launch(void* const* d_in, const int* in_sizes, int n_in,
                              void* d_out, int out_size, void* d_ws, size_t ws_size,
                              hipStream_t stream)
{
  const float* x  = (const float*)d_in[0];
  const float* Wr = (const float*)d_in[1];
  const float* W1 = (const float*)d_in[2];
  const float* b1 = (const float*)d_in[3];
  const float* W2 = (const float*)d_in[4];
  const float* b2 = (const float*)d_in[5];
  float* out = (float*)d_out;

  char* p = (char*)d_ws;
  auto alloc = [&](size_t bytes) {
    char* q = p; p += (bytes + 255) & ~(size_t)255; return q;
  };
  unsigned short* W1t = (unsigned short*)alloc((size_t)NEXP * DM * DE * 2);       // (E, DE, DM)
  unsigned short* W2t = (unsigned short*)alloc((size_t)NEXP * DM * DE * 2);       // (E, DM, DE)
  unsigned short* buf = (unsigned short*)alloc((size_t)NEXP * CAP * DM * 2);      // (E, cap, DM)
  unsigned short* h   = (unsigned short*)alloc((size_t)NEXP * CAP * DE * 2);      // (E, cap, DE)
  unsigned short* eo2 = (unsigned short*)alloc((size_t)2 * NEXP * CAP * DM * 2);  // (2, E, cap, DM)
  int*   topk = (int*)alloc((size_t)N_TOK * 2 * 4);
  float* tkw  = (float*)alloc((size_t)N_TOK * 2 * 4);
  int*   posk = (int*)alloc((size_t)N_TOK * 2 * 4);
  float* wts  = (float*)alloc((size_t)N_TOK * 2 * 4);
  int*   inv  = (int*)alloc((size_t)NEXP * CAP * 4);
  int*   kept = (int*)alloc((size_t)NEXP * 4);
  float* zP   = (float*)alloc((size_t)512 * 9 * 4);

  transpose_to_bf16<<<dim3(DE / 64, DM / 64, NEXP), 256, 0, stream>>>(W1, W1t, DM, DE);
  transpose_to_bf16<<<dim3(DM / 64, DE / 64, NEXP), 256, 0, stream>>>(W2, W2t, DE, DM);
  router_kernel<<<512, 256, 0, stream>>>(x, Wr, topk, tkw, zP);
  scan_kernel<<<1, 512, 0, stream>>>((const int2*)topk, (const float2*)tkw, posk, wts, inv, kept);
  dispatch_kernel<<<NEXP * CAP, 256, 0, stream>>>(x, inv, buf);

  // GEMM1: 2-barrier schedule, K=DM=1024. 10m x 16n x 8e = 1280 wgs.
  gemm2b<true, true><<<1280, 512, 0, stream>>>(
      buf, W1t, b1, h, kept, CAP, DE, DM, DM, 10, 16, 1, 1280);
  // GEMM2: 2-barrier schedule, split-K=2 (K=2048 each, lda=DE). 640 wgs.
  gemm2b<false, false><<<640, 512, 0, stream>>>(
      h, W2t, nullptr, eo2, kept, CAP, DM, DE / 2, DE, 10, 4, 2, 640);

  combine_kernel<<<N_TOK, 256, 0, stream>>>(eo2, b2, posk, wts, topk, zP, kept,
                                            out, out + (size_t)N_TOK * DM);
}

// Round 12
// 529.233 us; speedup vs baseline: 1.2025x; 1.0511x over previous
//
#include <hip/hip_runtime.h>
#include <stdint.h>

#define N_TOK    8192
#define DM       1024      // D_MODEL
#define DE       4096      // D_EXPERT
#define NEXP     8
#define CAP      2560
#define AUX_CO   0.01f
#define Z_CO     0.001f

typedef __attribute__((ext_vector_type(4))) float f32x4;
typedef __attribute__((ext_vector_type(8))) __bf16 bf16x8;

static __device__ __forceinline__ unsigned short f2bf(float f) {
  union { float f; uint32_t u; } v; v.f = f;
  uint32_t r = 0x7fffu + ((v.u >> 16) & 1u);
  return (unsigned short)((v.u + r) >> 16);
}
static __device__ __forceinline__ float bf2f(unsigned short u) {
  union { uint32_t u; float f; } v; v.u = ((uint32_t)u) << 16;
  return v.f;
}

#define MEMFENCE() asm volatile("" ::: "memory")
#define BAR()    do { MEMFENCE(); __builtin_amdgcn_s_barrier(); MEMFENCE(); } while (0)
#define LGKM0()  asm volatile("s_waitcnt lgkmcnt(0)" ::: "memory")
#define VMW(N)   asm volatile("s_waitcnt vmcnt(" #N ")" ::: "memory")
#define GLD16(g, l) __builtin_amdgcn_global_load_lds( \
    (const __attribute__((address_space(1))) void*)(g), \
    (__attribute__((address_space(3))) void*)(l), 16, 0, 0)

// ------- transpose + fp32->bf16: in (R,C) -> out (C,R); 64x64 tiles, 16B ld/st -------
__global__ __launch_bounds__(256) void transpose_to_bf16(
    const float* __restrict__ in, unsigned short* __restrict__ out, int R, int C)
{
  __shared__ float tile[64][65];
  const size_t eoff = (size_t)blockIdx.z * R * C;
  const int bx = blockIdx.x * 64, by = blockIdx.y * 64;   // bx: C-dim, by: R-dim
  const int r = threadIdx.x >> 2, c16 = (threadIdx.x & 3) * 16;
#pragma unroll
  for (int j = 0; j < 4; ++j) {
    const float4 v = *(const float4*)&in[eoff + (size_t)(by + r) * C + bx + c16 + j * 4];
    tile[r][c16 + j * 4 + 0] = v.x; tile[r][c16 + j * 4 + 1] = v.y;
    tile[r][c16 + j * 4 + 2] = v.z; tile[r][c16 + j * 4 + 3] = v.w;
  }
  __syncthreads();
  const int oc = threadIdx.x >> 2, r16 = (threadIdx.x & 3) * 16;
#pragma unroll
  for (int half = 0; half < 2; ++half) {
    uint4 o;
    const int rb = r16 + half * 8;
    o.x = (uint32_t)f2bf(tile[rb + 0][oc]) | ((uint32_t)f2bf(tile[rb + 1][oc]) << 16);
    o.y = (uint32_t)f2bf(tile[rb + 2][oc]) | ((uint32_t)f2bf(tile[rb + 3][oc]) << 16);
    o.z = (uint32_t)f2bf(tile[rb + 4][oc]) | ((uint32_t)f2bf(tile[rb + 5][oc]) << 16);
    o.w = (uint32_t)f2bf(tile[rb + 6][oc]) | ((uint32_t)f2bf(tile[rb + 7][oc]) << 16);
    *(uint4*)&out[eoff + (size_t)(bx + oc) * R + by + rb] = o;
  }
}

// ---------------- router ----------------
__global__ __launch_bounds__(256) void router_kernel(
    const float* __restrict__ x, const float* __restrict__ Wr,
    int* __restrict__ topk, float* __restrict__ tkw, float* __restrict__ zP)
{
  const int tid = threadIdx.x, lane = tid & 63, wave = tid >> 6;
  float zacc = 0.f;
  float pacc[NEXP];
#pragma unroll
  for (int e = 0; e < NEXP; ++e) pacc[e] = 0.f;

  for (int it = 0; it < 4; ++it) {
    const int t = blockIdx.x * 16 + it * 4 + wave;
    float acc[NEXP];
#pragma unroll
    for (int e = 0; e < NEXP; ++e) acc[e] = 0.f;
    const f32x4* x4 = (const f32x4*)(x + (size_t)t * DM);
#pragma unroll
    for (int i = 0; i < 4; ++i) {
      f32x4 xv = x4[i * 64 + lane];
#pragma unroll
      for (int j = 0; j < 4; ++j) {
        const float xs = xv[j];
        const float* wr = Wr + (size_t)((i * 64 + lane) * 4 + j) * NEXP;
#pragma unroll
        for (int e = 0; e < NEXP; ++e) acc[e] += xs * wr[e];
      }
    }
#pragma unroll
    for (int m = 32; m; m >>= 1)
#pragma unroll
      for (int e = 0; e < NEXP; ++e) acc[e] += __shfl_xor(acc[e], m);

    float mx = acc[0];
#pragma unroll
    for (int e = 1; e < NEXP; ++e) mx = fmaxf(mx, acc[e]);
    float p[NEXP], s = 0.f;
#pragma unroll
    for (int e = 0; e < NEXP; ++e) { p[e] = expf(acc[e] - mx); s += p[e]; }
    const float lse = mx + logf(s);
    zacc += lse * lse;
    const float inv_s = 1.f / s;
#pragma unroll
    for (int e = 0; e < NEXP; ++e) pacc[e] += p[e] * inv_s;

    int e0 = 0; float v0 = p[0];
#pragma unroll
    for (int e = 1; e < NEXP; ++e) if (p[e] > v0) { v0 = p[e]; e0 = e; }
    int e1 = -1; float v1 = -1.f;
#pragma unroll
    for (int e = 0; e < NEXP; ++e) if (e != e0 && p[e] > v1) { v1 = p[e]; e1 = e; }

    const float pr0 = v0 * inv_s, pr1 = v1 * inv_s;
    const float denom = fmaxf(pr0 + pr1, 1e-9f);
    if (lane == 0) {
      topk[2*t]   = e0; topk[2*t+1] = e1;
      tkw[2*t]    = pr0 / denom; tkw[2*t+1] = pr1 / denom;
    }
  }
  __shared__ float blk[4][9];
  if (lane == 0) {
    blk[wave][0] = zacc;
#pragma unroll
    for (int e = 0; e < NEXP; ++e) blk[wave][1 + e] = pacc[e];
  }
  __syncthreads();
  if (tid < 9)
    zP[blockIdx.x * 9 + tid] = blk[0][tid] + blk[1][tid] + blk[2][tid] + blk[3][tid];
}

// -------- scan: FCFS capacity positions; topk/tkw staged in LDS; inv tail-fill fused --------
__global__ __launch_bounds__(512) void scan_kernel(
    const int2* __restrict__ topk, const float2* __restrict__ tkw,
    int* __restrict__ posk, float* __restrict__ wts,
    int* __restrict__ inv, int* __restrict__ kept)
{
  __shared__ int2   stopk[N_TOK];
  __shared__ float2 stkw[N_TOK];
  const int tid = threadIdx.x;
  for (int j = tid; j < N_TOK; j += 512) { stopk[j] = topk[j]; stkw[j] = tkw[j]; }
  __syncthreads();

  const int lane = tid & 63;
  const int e = tid >> 6;                   // 8 waves = 8 experts
  int base = 0;
  const uint64_t below = (lane == 63) ? 0xFFFFFFFFFFFFFFFFull >> 1
                                      : ((1ull << lane) - 1ull);
  for (int i = 0; i < N_TOK / 64; ++i) {
    const int t = i * 64 + lane;
    const int2 ti = stopk[t];
    const float2 w = stkw[t];
    const bool hit = (ti.x == e) || (ti.y == e);
    const uint64_t m = __ballot(hit);
    if (hit) {
      const int pos = base + (int)__popcll(m & below);
      const bool kp = pos < CAP;
      const int k = (ti.x == e) ? 0 : 1;
      posk[2*t + k] = kp ? pos : CAP;
      wts[2*t + k]  = kp ? ((k == 0) ? w.x : w.y) : 0.f;
      if (kp) inv[e * CAP + pos] = t;
    }
    base += (int)__popcll(m);
  }
  const int tail = base < CAP ? base : CAP;
  for (int q = tail + lane; q < CAP; q += 64) inv[e * CAP + q] = -1;
  if (lane == 0) kept[e] = tail;
}

// ---------------- dispatch ----------------
__global__ __launch_bounds__(256) void dispatch_kernel(
    const float* __restrict__ x, const int* __restrict__ inv,
    unsigned short* __restrict__ buf)
{
  const int slot = blockIdx.x;
  const int t = inv[slot];
  ushort4 o;
  if (t >= 0) {
    const f32x4 v = ((const f32x4*)(x + (size_t)t * DM))[threadIdx.x];
    o.x = f2bf(v[0]); o.y = f2bf(v[1]); o.z = f2bf(v[2]); o.w = f2bf(v[3]);
  } else {
    o.x = 0; o.y = 0; o.z = 0; o.w = 0;
  }
  ((ushort4*)(buf + (size_t)slot * DM))[threadIdx.x] = o;
}

// ========== 128x256 / BK=32 grouped GEMM, 48KB LDS -> 2 blocks/CU (TLP) ==========
// 2-barrier race-safe skeleton, counted VMW(3); per-wave 64x64 (acc=64 VGPR);
// granule swizzle slot = kgrp ^ ((row>>1)&3): 8 lanes per 4-bank group (balanced).
template<bool RELU, bool BIAS>
__global__ __launch_bounds__(512, 4) void gemmT(
    const unsigned short* __restrict__ A,
    const unsigned short* __restrict__ Bt,
    const float* __restrict__ bias,         // (E, N) or null
    unsigned short* __restrict__ C,         // (nsplit, E, M, N) bf16
    const int* __restrict__ kept,
    int M, int N, int K, int lda, int mt, int nt, int nsplit, int nwg)
{
  __shared__ __attribute__((aligned(16))) unsigned short As[2 * 4096];   // 2 x 128x32
  __shared__ __attribute__((aligned(16))) unsigned short Bs[2 * 8192];   // 2 x 256x32
  const int tid = threadIdx.x, lane = tid & 63, wave = tid >> 6;
  const int wr = wave >> 2, wc = wave & 3;   // 2M x 4N, per-wave 64x64 output
  const int frow = lane & 15, kgrp = lane >> 4;

  int wg = (int)blockIdx.x;                  // bijective XCD chunking (nwg%8==0)
  wg = (wg & 7) * (nwg >> 3) + (wg >> 3);
  const int ntpe = mt * nt;
  const int bpe = ntpe * nsplit;
  const int e = wg / bpe;
  const int rem = wg % bpe;
  const int split = rem / ntpe;
  const int rr = rem % ntpe;
  const int m0 = (rr / nt) * 128;
  const int n0 = (rr % nt) * 256;
  if (m0 >= kept[e]) return;

  const unsigned short* Ae = A  + (size_t)e * M * lda + (size_t)m0 * lda + (size_t)split * K;
  const unsigned short* Be = Bt + (size_t)e * N * lda + (size_t)n0 * lda + (size_t)split * K;

  const int srow = tid >> 2;                 // 0..127
  const int sg   = tid & 3;                  // granule slot 0..3

  // LDS slot s holds global granule g = s ^ ((row>>1)&3); dest linear, source pre-swizzled
  auto stage = [&](int t) {                  // 3 global_load_lds per thread
    const int c = t & 1, k0 = t * 32;
    {
      const int gcol = sg ^ ((srow >> 1) & 3);
      GLD16(Ae + (size_t)srow * lda + (k0 + gcol * 8), &As[c * 4096 + tid * 8]);
    }
#pragma unroll
    for (int i = 0; i < 2; ++i) {
      const int row = i * 128 + srow;
      const int gcol = sg ^ ((row >> 1) & 3);
      GLD16(Be + (size_t)row * lda + (k0 + gcol * 8), &Bs[c * 8192 + i * 4096 + tid * 8]);
    }
  };
  auto rdA = [&](bf16x8* dst, int c) {       // 4 ds_read_b128
#pragma unroll
    for (int m = 0; m < 4; ++m) {
      const int row = wr * 64 + m * 16 + frow;
      dst[m] = *(const bf16x8*)&As[c * 4096 + row * 32 + ((kgrp ^ ((row >> 1) & 3)) * 8)];
    }
  };
  auto rdB = [&](bf16x8* dst, int c) {       // 4 ds_read_b128
#pragma unroll
    for (int n = 0; n < 4; ++n) {
      const int row = wc * 64 + n * 16 + frow;
      dst[n] = *(const bf16x8*)&Bs[c * 8192 + row * 32 + ((kgrp ^ ((row >> 1) & 3)) * 8)];
    }
  };

  f32x4 acc[4][4];
#pragma unroll
  for (int m = 0; m < 4; ++m)
#pragma unroll
    for (int n = 0; n < 4; ++n) acc[m][n] = (f32x4){0.f, 0.f, 0.f, 0.f};
  bf16x8 af[4], bq[4];

  const int nk = K >> 5;

  stage(0); stage(1);                        // 6 outstanding

  for (int t = 0; t < nk; ++t) {
    const int c = t & 1;
    // tile-t loads (issued 2 tiles ago) ready; keep stage(t+1)'s 3 in flight
    if (t + 2 <= nk) { VMW(3); } else { VMW(0); }
    BAR();
    rdA(af, c);
    rdB(bq, c);
    LGKM0();                                 // this wave's reads done
    BAR();                                   // ALL waves' reads of buf c done
    if (t + 2 < nk) stage(t + 2);            // safe to overwrite buf c
    __builtin_amdgcn_s_setprio(1);
#pragma unroll
    for (int m = 0; m < 4; ++m)
#pragma unroll
      for (int n = 0; n < 4; ++n)
        acc[m][n] = __builtin_amdgcn_mfma_f32_16x16x32_bf16(af[m], bq[n], acc[m][n], 0, 0, 0);
    __builtin_amdgcn_s_setprio(0);
  }

  // epilogue: D row = 4*kgrp + reg (m89/m91), col = frow
  unsigned short* Ce = C + (size_t)(split * NEXP + e) * M * N;
  const int r0 = m0 + wr * 64 + 4 * kgrp;
  const int c0 = n0 + wc * 64 + frow;
#pragma unroll
  for (int nf = 0; nf < 4; ++nf) {
    const int cc = c0 + nf * 16;
    float bv = 0.f;
    if (BIAS) bv = bias[(size_t)e * N + cc];
#pragma unroll
    for (int m = 0; m < 4; ++m) {
#pragma unroll
      for (int r = 0; r < 4; ++r) {
        float v = acc[m][nf][r] + bv;
        if (RELU) v = fmaxf(v, 0.f);
        Ce[(size_t)(r0 + m * 16 + r) * N + cc] = f2bf(v);
      }
    }
  }
}

// ------- combine: sum split-K partials + b2, weight by top-2; finalize fused in blk 0 -------
__global__ __launch_bounds__(256) void combine_kernel(
    const unsigned short* __restrict__ eo2,   // (2, E, CAP, DM) bf16 partials
    const float* __restrict__ b2,             // (E, DM)
    const int* __restrict__ posk, const float* __restrict__ wts,
    const int* __restrict__ topk,
    const float* __restrict__ zP, const int* __restrict__ kept,
    float* __restrict__ out, float* __restrict__ outs)
{
  const int t = blockIdx.x;
  const int e0 = topk[2*t], e1 = topk[2*t+1];
  int p0 = posk[2*t], p1 = posk[2*t+1];
  p0 = p0 < CAP - 1 ? p0 : CAP - 1;
  p1 = p1 < CAP - 1 ? p1 : CAP - 1;
  const float w0 = wts[2*t], w1 = wts[2*t+1];
  const size_t o0 = ((size_t)e0 * CAP + p0) * DM;
  const size_t o1 = ((size_t)e1 * CAP + p1) * DM;
  const size_t sp = (size_t)NEXP * CAP * DM;
  const ushort4 a0 = ((const ushort4*)(eo2 + o0))[threadIdx.x];
  const ushort4 a1 = ((const ushort4*)(eo2 + sp + o0))[threadIdx.x];
  const ushort4 c0 = ((const ushort4*)(eo2 + o1))[threadIdx.x];
  const ushort4 c1 = ((const ushort4*)(eo2 + sp + o1))[threadIdx.x];
  const f32x4 bv0 = ((const f32x4*)(b2 + (size_t)e0 * DM))[threadIdx.x];
  const f32x4 bv1 = ((const f32x4*)(b2 + (size_t)e1 * DM))[threadIdx.x];
  f32x4 o;
  o[0] = w0 * (bf2f(a0.x) + bf2f(a1.x) + bv0[0]) + w1 * (bf2f(c0.x) + bf2f(c1.x) + bv1[0]);
  o[1] = w0 * (bf2f(a0.y) + bf2f(a1.y) + bv0[1]) + w1 * (bf2f(c0.y) + bf2f(c1.y) + bv1[1]);
  o[2] = w0 * (bf2f(a0.z) + bf2f(a1.z) + bv0[2]) + w1 * (bf2f(c0.z) + bf2f(c1.z) + bv1[2]);
  o[3] = w0 * (bf2f(a0.w) + bf2f(a1.w) + bv0[3]) + w1 * (bf2f(c0.w) + bf2f(c1.w) + bv1[3]);
  ((f32x4*)(out + (size_t)t * DM))[threadIdx.x] = o;

  if (t == 0 && threadIdx.x < 64) {
    const int lane = threadIdx.x;
    float v[9];
#pragma unroll
    for (int e = 0; e < 9; ++e) {
      float s = 0.f;
      for (int bk = 0; bk < 8; ++bk) s += zP[(lane * 8 + bk) * 9 + e];
      v[e] = s;
    }
#pragma unroll
    for (int m = 32; m; m >>= 1)
#pragma unroll
      for (int e = 0; e < 9; ++e) v[e] += __shfl_xor(v[e], m);
    if (lane == 0) {
      const float z = v[0] / (float)N_TOK;
      float total = 0.f;
      for (int e = 0; e < NEXP; ++e) total += (float)kept[e];
      total = fmaxf(total, 1.f);
      float aux = 0.f;
      for (int e = 0; e < NEXP; ++e)
        aux += ((float)kept[e] / total) * (v[1 + e] / (float)N_TOK);
      aux *= (float)NEXP;
      outs[0] = aux;
      outs[1] = z;
      outs[2] = AUX_CO * aux + Z_CO * z;
    }
  }
}

extern "C" void kernel_launch(void* const* d_in, const int* in_sizes, int n_in,
                              void* d_out, int out_size, void* d_ws, size_t ws_size,
                              hipStream_t stream)
{
  const float* x  = (const float*)d_in[0];
  const float* Wr = (const float*)d_in[1];
  const float* W1 = (const float*)d_in[2];
  const float* b1 = (const float*)d_in[3];
  const float* W2 = (const float*)d_in[4];
  const float* b2 = (const float*)d_in[5];
  float* out = (float*)d_out;

  char* p = (char*)d_ws;
  auto alloc = [&](size_t bytes) {
    char* q = p; p += (bytes + 255) & ~(size_t)255; return q;
  };
  unsigned short* W1t = (unsigned short*)alloc((size_t)NEXP * DM * DE * 2);       // (E, DE, DM)
  unsigned short* W2t = (unsigned short*)alloc((size_t)NEXP * DM * DE * 2);       // (E, DM, DE)
  unsigned short* buf = (unsigned short*)alloc((size_t)NEXP * CAP * DM * 2);      // (E, cap, DM)
  unsigned short* h   = (unsigned short*)alloc((size_t)NEXP * CAP * DE * 2);      // (E, cap, DE)
  unsigned short* eo2 = (unsigned short*)alloc((size_t)2 * NEXP * CAP * DM * 2);  // (2, E, cap, DM)
  int*   topk = (int*)alloc((size_t)N_TOK * 2 * 4);
  float* tkw  = (float*)alloc((size_t)N_TOK * 2 * 4);
  int*   posk = (int*)alloc((size_t)N_TOK * 2 * 4);
  float* wts  = (float*)alloc((size_t)N_TOK * 2 * 4);
  int*   inv  = (int*)alloc((size_t)NEXP * CAP * 4);
  int*   kept = (int*)alloc((size_t)NEXP * 4);
  float* zP   = (float*)alloc((size_t)512 * 9 * 4);

  transpose_to_bf16<<<dim3(DE / 64, DM / 64, NEXP), 256, 0, stream>>>(W1, W1t, DM, DE);
  transpose_to_bf16<<<dim3(DM / 64, DE / 64, NEXP), 256, 0, stream>>>(W2, W2t, DE, DM);
  router_kernel<<<512, 256, 0, stream>>>(x, Wr, topk, tkw, zP);
  scan_kernel<<<1, 512, 0, stream>>>((const int2*)topk, (const float2*)tkw, posk, wts, inv, kept);
  dispatch_kernel<<<NEXP * CAP, 256, 0, stream>>>(x, inv, buf);

  // GEMM1: 128x256/BK32, 2 blocks/CU. 20m x 16n x 8e = 2560 wgs = 5 exact rounds.
  gemmT<true, true><<<2560, 512, 0, stream>>>(
      buf, W1t, b1, h, kept, CAP, DE, DM, DM, 20, 16, 1, 2560);
  // GEMM2: same structure, split-K=2 (K=2048 each, lda=DE). 20m x 4n x 2k x 8e = 1280 wgs.
  gemmT<false, false><<<1280, 512, 0, stream>>>(
      h, W2t, nullptr, eo2, kept, CAP, DM, DE / 2, DE, 20, 4, 2, 1280);

  combine_kernel<<<N_TOK, 256, 0, stream>>>(eo2, b2, posk, wts, topk, zP, kept,
                                            out, out + (size_t)N_TOK * DM);
}